// Round 9
// baseline (9794.301 us; speedup 1.0000x reference)
//
#include <hip/hip_runtime.h>

#define TT 2048
#define BB 64
#define INF 32
#define HH 512
#define OO 32

typedef unsigned long long u64;

__device__ __forceinline__ float sigm(float x) {
  return 1.f / (1.f + __expf(-x));
}
__device__ __forceinline__ float tanh_(float x) {
  float e = __expf(2.f * x);
  return 1.f - 2.f / (1.f + e);
}

// Coherent (L1/L2-bypassing) 16B load from the coherence point (IF$).
#define COH_LOAD4(dst, ptr)                                                  \
  asm volatile("global_load_dwordx4 %0, %1, off sc0 sc1"                     \
               : "=v"(dst) : "v"(ptr))

// Bounded spin: legit waits are ~µs; guard guarantees termination even under
// a protocol bug (wrong answer beats wedged GPU).
#define SPIN_LIMIT 20000

// LDS h-buffer: 8 batches x 64 k-groups, each group 8 floats + 4 pad words.
// Measured (R5/R7/R8): SQ_LDS_BANK_CONFLICT == 0 with this layout.
#define HGRP 12
#define HB_STRIDE (64 * HGRP)  // 768 words per batch

// Protocol: h exchanged as (float h, int tag) 8-byte pairs in hpair[2][64][512].
// Owner of (jj,b) at end of step t stores {h_t, tag=t+1} into slot t&1 with ONE
// relaxed agent-scope 8B atomic store. Reader at step t polls its own pairs in
// slot (t-1)&1 until tag==t; the polling load IS the data load (no flags, no
// fences, no separate h fetch). Reuse-safety: a writer reaches tag t+2 for slot
// p only after observing all 32 slices at t+1, each published only after that
// WG finished reading slot p at tag t => readers never see a future tag.
//
// RULE-20 NOTE: every index into v[] below MUST be compile-time constant
// after unrolling. A single runtime index (R5's "jb" form) sends the whole
// array to scratch: measured 176 GB WRITE_SIZE, 4.6x slowdown (R5/R6/R7).
__global__ __launch_bounds__(512, 2)
void lstm_fused(const float* __restrict__ X,
                const float* __restrict__ h0,
                const float* __restrict__ c0,
                const float* __restrict__ Wih,
                const float* __restrict__ Whh,
                const float* __restrict__ bih,
                const float* __restrict__ bhh,
                const float* __restrict__ Wout,
                const float* __restrict__ bout,
                float* __restrict__ outp,
                float* __restrict__ hT,
                float* __restrict__ cT,
                u64* __restrict__ hpair)    // [2][64][512] (h,tag) pairs, zeroed per launch
{
  const int tid    = threadIdx.x;
  const int rg     = tid >> 6;
  const int lane   = tid & 63;
  const int bg     = blockIdx.x & 7;
  const int sl     = blockIdx.x >> 3;
  const int k0     = lane << 3;
  const int bglob0 = bg << 3;

  __shared__ float gsh[512];                 // gates [r(64)][b(8)]
  __shared__ float hlds[8 * HB_STRIDE];      // staged h, padded (24 KB)

  // ---- persistent weights in registers ----
  float w[8][8];
  float wih[8];
  const int ink = lane & 31;
#pragma unroll
  for (int rr = 0; rr < 8; ++rr) {
    int r = (rg << 3) + rr;
    int grow = ((r >> 4) << 9) + (sl << 4) + (r & 15);
    const float4* wp = (const float4*)(Whh + (size_t)grow * HH + k0);
    float4 a = wp[0], b4 = wp[1];
    w[rr][0] = a.x;  w[rr][1] = a.y;  w[rr][2] = a.z;  w[rr][3] = a.w;
    w[rr][4] = b4.x; w[rr][5] = b4.y; w[rr][6] = b4.z; w[rr][7] = b4.w;
    wih[rr] = Wih[grow * INF + ink];
  }
  float wout[8];
  {
    const float4* wp = (const float4*)(Wout + sl * HH + k0);
    float4 a = wp[0], b4 = wp[1];
    wout[0] = a.x;  wout[1] = a.y;  wout[2] = a.z;  wout[3] = a.w;
    wout[4] = b4.x; wout[5] = b4.y; wout[6] = b4.z; wout[7] = b4.w;
  }
  float bsum, bo = bout[sl];
  {
    int r = (rg << 3) + (lane >> 3);
    int grow = ((r >> 4) << 9) + (sl << 4) + (r & 15);
    bsum = bih[grow] + bhh[grow];
  }

  const bool owner = (tid < 128);
  const int ojj = tid >> 3, ob = tid & 7;
  const int hoff_owner = (bglob0 + ob) * HH + (sl << 4) + ojj;
  float cst = owner ? c0[hoff_owner] : 0.f;

  // cooperative-stage mapping: thread handles batch lb, k-group lg (8 values)
  const int lb = tid >> 6;
  const int lg = tid & 63;

  for (int t = 0; t < TT; ++t) {
    // ---- X prefetch (runtime math in the ADDRESS, never the reg index) ----
    float xv[4];
    {
      const float* xr = X + (size_t)t * BB * INF + bglob0 * INF + ink;
      const int jb = (lane >= 32) ? 4 : 0;
#pragma unroll
      for (int j = 0; j < 4; ++j) xv[j] = xr[(jb + j) * INF];
    }

    // ---- stage h_{t-1}: poll own (h,tag) pairs; the poll IS the load ----
    if (t == 0) {
      const float* hp = h0 + (size_t)(bglob0 + lb) * HH + (lg << 3);
      float4 ha = ((const float4*)hp)[0];
      float4 hb = ((const float4*)hp)[1];
      float* dst = hlds + lb * HB_STRIDE + lg * HGRP;
      *(float4*)(dst)     = ha;
      *(float4*)(dst + 4) = hb;
    } else {
      const u64* base = hpair + (size_t)((t - 1) & 1) * BB * HH
                        + (size_t)(bglob0 + lb) * HH + (lg << 3);
      int4 p0, p1, p2, p3;
      int guard = 0;
      for (;;) {
        COH_LOAD4(p0, base);
        COH_LOAD4(p1, base + 2);
        COH_LOAD4(p2, base + 4);
        COH_LOAD4(p3, base + 6);
        asm volatile("s_waitcnt vmcnt(0)" ::: "memory");
        __builtin_amdgcn_sched_barrier(0);
        bool ok = (p0.y == t) & (p0.w == t) & (p1.y == t) & (p1.w == t) &
                  (p2.y == t) & (p2.w == t) & (p3.y == t) & (p3.w == t);
        if (ok || ++guard > SPIN_LIMIT) break;
        __builtin_amdgcn_s_sleep(1);
      }
      float* dst = hlds + lb * HB_STRIDE + lg * HGRP;
      *(float4*)(dst) = make_float4(__int_as_float(p0.x), __int_as_float(p0.z),
                                    __int_as_float(p1.x), __int_as_float(p1.z));
      *(float4*)(dst + 4) = make_float4(__int_as_float(p2.x), __int_as_float(p2.z),
                                        __int_as_float(p3.x), __int_as_float(p3.z));
    }
    __syncthreads();  // barrier A2: staged h visible; also orders gsh/hlds reuse

    // ---- accumulators live ONLY from here to the gsh store ----
    float v[64];
#pragma unroll
    for (int i = 0; i < 64; ++i) v[i] = 0.f;
    float oacc = 0.f;

    // ---- recurrent dots: 8 batches x 8 rows x 8 k, LDS-fed register FMAs ----
#pragma unroll
    for (int b = 0; b < 8; ++b) {
      const float4* src = (const float4*)(hlds + b * HB_STRIDE + lane * HGRP);
      float4 a = src[0], b4 = src[1];
      float hk[8] = {a.x, a.y, a.z, a.w, b4.x, b4.y, b4.z, b4.w};
#pragma unroll
      for (int rr = 0; rr < 8; ++rr)
#pragma unroll
        for (int kk = 0; kk < 8; ++kk)
          v[rr * 8 + b] = __fmaf_rn(w[rr][kk], hk[kk], v[rr * 8 + b]);
      if (b == rg) {  // wave-uniform
#pragma unroll
        for (int kk = 0; kk < 8; ++kk) oacc = __fmaf_rn(hk[kk], wout[kk], oacc);
      }
    }

    // ---- input projection: COMPILE-TIME v-indices (rule #20) ----
    if (lane < 32) {
#pragma unroll
      for (int j = 0; j < 4; ++j)
#pragma unroll
        for (int rr = 0; rr < 8; ++rr)
          v[rr * 8 + j] = __fmaf_rn(wih[rr], xv[j], v[rr * 8 + j]);
    } else {
#pragma unroll
      for (int j = 0; j < 4; ++j)
#pragma unroll
        for (int rr = 0; rr < 8; ++rr)
          v[rr * 8 + 4 + j] = __fmaf_rn(wih[rr], xv[j], v[rr * 8 + 4 + j]);
    }

    // ---- butterfly reduce over 64 k-chunk lanes; lane ends with idx==lane ----
#pragma unroll
    for (int i = 0; i < 32; ++i) {
      float a = v[i], b = v[i + 32];
      asm("v_permlane32_swap_b32 %0, %1" : "+v"(a), "+v"(b));
      v[i] = a + b;
    }
#pragma unroll
    for (int i = 0; i < 16; ++i) {
      float a = v[i], b = v[i + 16];
      asm("v_permlane16_swap_b32 %0, %1" : "+v"(a), "+v"(b));
      v[i] = a + b;
    }
#pragma unroll
    for (int s = 8; s >= 1; s >>= 1) {
      const bool hi = (lane & s) != 0;
#pragma unroll
      for (int i = 0; i < s; ++i) {
        float sent = hi ? v[i] : v[i + s];
        float keep = hi ? v[i + s] : v[i];
        v[i] = keep + __shfl_xor(sent, s, 64);
      }
    }
    gsh[(rg << 6) + lane] = v[0] + bsum;  // gates[r = rg*8+(lane>>3)][b = lane&7]
    __syncthreads();  // barrier B

    // ---- owners: nonlinearity, c/h update, single 8B (h,tag) publish ----
    u64* slotp = hpair + (size_t)(t & 1) * BB * HH;
    if (owner) {
      float gi = gsh[(ojj << 3) + ob];
      float gf = gsh[((16 + ojj) << 3) + ob];
      float gg = gsh[((32 + ojj) << 3) + ob];
      float go = gsh[((48 + ojj) << 3) + ob];
      float i_ = sigm(gi), f_ = sigm(gf), g_ = tanh_(gg), o_ = sigm(go);
      cst = __fmaf_rn(f_, cst, i_ * g_);
      float hv = o_ * tanh_(cst);
      u64 pk = ((u64)(unsigned)(t + 1) << 32) | (u64)(unsigned)__float_as_int(hv);
      __hip_atomic_store(&slotp[hoff_owner], pk, __ATOMIC_RELAXED,
                         __HIP_MEMORY_SCOPE_AGENT);
      if (t == TT - 1) { hT[hoff_owner] = hv; cT[hoff_owner] = cst; }
    }

    // ---- deferred: out-projection reduce (off the inter-WG critical path) ----
#pragma unroll
    for (int s = 32; s >= 1; s >>= 1) oacc += __shfl_xor(oacc, s, 64);
    if (t > 0 && lane == 0)
      outp[(size_t)(t - 1) * BB * OO + (bglob0 + rg) * OO + sl] = oacc + bo;
  }

  // ---- final output projection for h_{TT-1} -> outputs[TT-1] ----
  {
    const u64* base = hpair + (size_t)((TT - 1) & 1) * BB * HH
                      + (size_t)(bglob0 + rg) * HH + k0;
    int4 p0, p1, p2, p3;
    int guard = 0;
    for (;;) {
      COH_LOAD4(p0, base);
      COH_LOAD4(p1, base + 2);
      COH_LOAD4(p2, base + 4);
      COH_LOAD4(p3, base + 6);
      asm volatile("s_waitcnt vmcnt(0)" ::: "memory");
      __builtin_amdgcn_sched_barrier(0);
      bool ok = (p0.y == TT) & (p0.w == TT) & (p1.y == TT) & (p1.w == TT) &
                (p2.y == TT) & (p2.w == TT) & (p3.y == TT) & (p3.w == TT);
      if (ok || ++guard > SPIN_LIMIT) break;
      __builtin_amdgcn_s_sleep(1);
    }
    float oacc = __int_as_float(p0.x) * wout[0] + __int_as_float(p0.z) * wout[1]
               + __int_as_float(p1.x) * wout[2] + __int_as_float(p1.z) * wout[3]
               + __int_as_float(p2.x) * wout[4] + __int_as_float(p2.z) * wout[5]
               + __int_as_float(p3.x) * wout[6] + __int_as_float(p3.z) * wout[7];
#pragma unroll
    for (int s = 32; s >= 1; s >>= 1) oacc += __shfl_xor(oacc, s, 64);
    if (lane == 0)
      outp[(size_t)(TT - 1) * BB * OO + (bglob0 + rg) * OO + sl] = oacc + bo;
  }
}

extern "C" void kernel_launch(void* const* d_in, const int* in_sizes, int n_in,
                              void* d_out, int out_size, void* d_ws, size_t ws_size,
                              hipStream_t stream) {
  const float* X    = (const float*)d_in[0];
  const float* h0   = (const float*)d_in[1];
  const float* c0   = (const float*)d_in[2];
  const float* Wih  = (const float*)d_in[3];
  const float* Whh  = (const float*)d_in[4];
  const float* bih  = (const float*)d_in[5];
  const float* bhh  = (const float*)d_in[6];
  const float* Wout = (const float*)d_in[7];
  const float* bout = (const float*)d_in[8];

  float* outp = (float*)d_out;                       // [T][B][OUT]
  float* hT   = outp + (size_t)TT * BB * OO;         // [B][H]
  float* cT   = hT + (size_t)BB * HH;                // [B][H]

  u64* hpair = (u64*)d_ws;                           // 2*64*512*8 = 512 KB

  // tags must be < 1 at every replay (graph-captured, runs each call)
  hipMemsetAsync(hpair, 0, (size_t)2 * BB * HH * sizeof(u64), stream);

  lstm_fused<<<dim3(256), dim3(512), 0, stream>>>(
      X, h0, c0, Wih, Whh, bih, bhh, Wout, bout, outp, hT, cT, hpair);
}

// Round 12
// 9214.829 us; speedup vs baseline: 1.0629x; 1.0629x over previous
//
#include <hip/hip_runtime.h>

#define TT 2048
#define BB 64
#define INF 32
#define HH 512
#define OO 32

__device__ __forceinline__ float sigm(float x) {
  return 1.f / (1.f + __expf(-x));
}
__device__ __forceinline__ float tanh_(float x) {
  float e = __expf(2.f * x);
  return 1.f - 2.f / (1.f + e);
}

// Coherent (L1/L2-bypassing) 16B load from the coherence point (IF$).
#define COH_LOAD4(dst, ptr)                                                  \
  asm volatile("global_load_dwordx4 %0, %1, off sc0 sc1"                     \
               : "=v"(dst) : "v"(ptr))

// Bounded spin: legit waits are ~µs; guard guarantees termination even under
// a protocol bug (wrong answer beats wedged GPU).
#define SPIN_LIMIT 20000

// LDS h-buffer: 8 batches x 64 k-groups, each group 8 floats + 4 pad words.
// Measured (R5/R7/R8): SQ_LDS_BANK_CONFLICT == 0 with this layout.
#define HGRP 12
#define HB_STRIDE (64 * HGRP)  // 768 words per batch

// grid = 256 WGs: bg = blockIdx&7 (8 batches), sl = blockIdx>>3 (16 h-idx).
// block = 512 thr: wave rg owns local rows [rg*8, rg*8+8) (R8 mapping,
// VALIDATED: grow(r) = (r>>4)*512 + sl*16 + (r&15), r = rg*8+rr).
// NOTE: R10/R11's gate-interleaved remap + in-wave shfl gather FAILED
// (absmax 0.125, deterministic, twice) — do not resurrect.
//
// Protocol R12: h published via relaxed agent-scope stores (write-through to
// IF$). Owners all live in waves 0-1, so each owner WAVE drains its own
// stores (s_waitcnt vmcnt(0)) and publishes its own flag flags[bg][sl*2+rg]
// — NO barrier C. Readers poll all 64 flags of their bg (wave 0), then
// cooperatively stage h via sc0/sc1 coherent loads into LDS. No fences.
// WAR safety without C: hlds is re-written at stage_{t+1} only after
// barrier A_{t+1}; every wave reached A only after passing B_t, which is
// after all hlds reads of dot_t. Ring-slot reuse: flag=t+2 implies that WG
// passed B_{t+1} >= stage_{t+1} (its ring reads of slot t&1).
//
// RULE-20 NOTE: every index into v[] below MUST be compile-time constant
// after unrolling. A single runtime index (R5's "jb" form) sends the whole
// array to scratch: measured 176 GB WRITE_SIZE, 4.6x slowdown (R5/R6/R7).
__global__ __launch_bounds__(512, 2)
void lstm_fused(const float* __restrict__ X,
                const float* __restrict__ h0,
                const float* __restrict__ c0,
                const float* __restrict__ Wih,
                const float* __restrict__ Whh,
                const float* __restrict__ bih,
                const float* __restrict__ bhh,
                const float* __restrict__ Wout,
                const float* __restrict__ bout,
                float* __restrict__ outp,
                float* __restrict__ hT,
                float* __restrict__ cT,
                float* __restrict__ hring,   // [2][64][512] fp32
                int* __restrict__ flags)     // [8][64] monotonic, zeroed per launch
{
  const int tid    = threadIdx.x;
  const int rg     = tid >> 6;
  const int lane   = tid & 63;
  const int bg     = blockIdx.x & 7;
  const int sl     = blockIdx.x >> 3;
  const int k0     = lane << 3;
  const int bglob0 = bg << 3;

  __shared__ float gsh[512];                 // gates [r(64)][b(8)]
  __shared__ float hlds[8 * HB_STRIDE];      // staged h, padded (24 KB)

  // ---- persistent weights in registers (R8-validated grow mapping) ----
  float w[8][8];
  float wih[8];
  const int ink = lane & 31;
#pragma unroll
  for (int rr = 0; rr < 8; ++rr) {
    int r = (rg << 3) + rr;
    int grow = ((r >> 4) << 9) + (sl << 4) + (r & 15);
    const float4* wp = (const float4*)(Whh + (size_t)grow * HH + k0);
    float4 a = wp[0], b4 = wp[1];
    w[rr][0] = a.x;  w[rr][1] = a.y;  w[rr][2] = a.z;  w[rr][3] = a.w;
    w[rr][4] = b4.x; w[rr][5] = b4.y; w[rr][6] = b4.z; w[rr][7] = b4.w;
    wih[rr] = Wih[grow * INF + ink];
  }
  float wout[8];
  {
    const float4* wp = (const float4*)(Wout + sl * HH + k0);
    float4 a = wp[0], b4 = wp[1];
    wout[0] = a.x;  wout[1] = a.y;  wout[2] = a.z;  wout[3] = a.w;
    wout[4] = b4.x; wout[5] = b4.y; wout[6] = b4.z; wout[7] = b4.w;
  }
  float bsum, bo = bout[sl];
  {
    int r = (rg << 3) + (lane >> 3);
    int grow = ((r >> 4) << 9) + (sl << 4) + (r & 15);
    bsum = bih[grow] + bhh[grow];
  }

  // owners: tid<128 (waves 0-1), state for (jj = tid>>3, b = tid&7)
  const bool ownerw = (rg < 2);
  const int ojj = tid >> 3, ob = tid & 7;
  const int hoff_owner = (bglob0 + ob) * HH + (sl << 4) + ojj;
  float cst = (ownerw) ? c0[hoff_owner] : 0.f;

  // cooperative-stage mapping: thread handles batch lb, k-group lg
  const int lb = tid >> 6;
  const int lg = tid & 63;

  int* myflags = flags + (bg << 6);

  for (int t = 0; t < TT; ++t) {
    // ---- X prefetch (runtime math in the ADDRESS, never the reg index) ----
    float xv[4];
    {
      const float* xr = X + (size_t)t * BB * INF + bglob0 * INF + ink;
      const int jb = (lane >= 32) ? 4 : 0;
#pragma unroll
      for (int j = 0; j < 4; ++j) xv[j] = xr[(jb + j) * INF];
    }

    // ---- wait: all 32 WGs x 2 owner-waves of my bg published step t-1 ----
    if (t > 0 && rg == 0) {
      int f = __hip_atomic_load(&myflags[lane], __ATOMIC_RELAXED,
                                __HIP_MEMORY_SCOPE_AGENT);
      int guard = 0;
      while (__any(f < t)) {
        if (++guard > SPIN_LIMIT) break;   // uniform across wave
        __builtin_amdgcn_s_sleep(1);
        f = __hip_atomic_load(&myflags[lane], __ATOMIC_RELAXED,
                              __HIP_MEMORY_SCOPE_AGENT);
      }
    }
    __syncthreads();  // barrier A: everyone sees flags>=t (via wave 0)

    // ---- cooperative coherent load of h_{t-1} (16 KB once per WG) ----
    {
      const float* hsrc = (t == 0) ? h0 : hring + (size_t)((t - 1) & 1) * BB * HH;
      const float* hp = hsrc + (size_t)(bglob0 + lb) * HH + (lg << 3);
      float4 ha, hb4;
      COH_LOAD4(ha, hp);
      COH_LOAD4(hb4, hp + 4);
      asm volatile("s_waitcnt vmcnt(0)" ::: "memory");
      __builtin_amdgcn_sched_barrier(0);
      float* dst = hlds + lb * HB_STRIDE + lg * HGRP;
      *(float4*)(dst)     = ha;
      *(float4*)(dst + 4) = hb4;
    }
    __syncthreads();  // barrier A2: staged h visible to all waves

    // ---- accumulators live ONLY from here to the gsh store ----
    float v[64];
#pragma unroll
    for (int i = 0; i < 64; ++i) v[i] = 0.f;
    float oacc = 0.f;

    // ---- recurrent dots: 8 batches x 8 rows x 8 k, LDS-fed register FMAs ----
#pragma unroll
    for (int b = 0; b < 8; ++b) {
      const float4* src = (const float4*)(hlds + b * HB_STRIDE + lane * HGRP);
      float4 a = src[0], b4 = src[1];
      float hk[8] = {a.x, a.y, a.z, a.w, b4.x, b4.y, b4.z, b4.w};
#pragma unroll
      for (int rr = 0; rr < 8; ++rr)
#pragma unroll
        for (int kk = 0; kk < 8; ++kk)
          v[rr * 8 + b] = __fmaf_rn(w[rr][kk], hk[kk], v[rr * 8 + b]);
      if (b == rg) {  // wave-uniform
#pragma unroll
        for (int kk = 0; kk < 8; ++kk) oacc = __fmaf_rn(hk[kk], wout[kk], oacc);
      }
    }

    // ---- input projection: COMPILE-TIME v-indices (rule #20) ----
    if (lane < 32) {
#pragma unroll
      for (int j = 0; j < 4; ++j)
#pragma unroll
        for (int rr = 0; rr < 8; ++rr)
          v[rr * 8 + j] = __fmaf_rn(wih[rr], xv[j], v[rr * 8 + j]);
    } else {
#pragma unroll
      for (int j = 0; j < 4; ++j)
#pragma unroll
        for (int rr = 0; rr < 8; ++rr)
          v[rr * 8 + 4 + j] = __fmaf_rn(wih[rr], xv[j], v[rr * 8 + 4 + j]);
    }

    // ---- butterfly reduce over 64 k-chunk lanes; lane ends with idx==lane ----
#pragma unroll
    for (int i = 0; i < 32; ++i) {
      float a = v[i], b = v[i + 32];
      asm("v_permlane32_swap_b32 %0, %1" : "+v"(a), "+v"(b));
      v[i] = a + b;
    }
#pragma unroll
    for (int i = 0; i < 16; ++i) {
      float a = v[i], b = v[i + 16];
      asm("v_permlane16_swap_b32 %0, %1" : "+v"(a), "+v"(b));
      v[i] = a + b;
    }
#pragma unroll
    for (int s = 8; s >= 1; s >>= 1) {
      const bool hi = (lane & s) != 0;
#pragma unroll
      for (int i = 0; i < s; ++i) {
        float sent = hi ? v[i] : v[i + s];
        float keep = hi ? v[i + s] : v[i];
        v[i] = keep + __shfl_xor(sent, s, 64);
      }
    }
    gsh[(rg << 6) + lane] = v[0] + bsum;  // gates[r = rg*8+(lane>>3)][b = lane&7]
    __syncthreads();  // barrier B (also closes hlds reads for WAR safety)

    // ---- owner waves: nonlinearity, c/h update, publish, OWN flag ----
    float* slotp = hring + (size_t)(t & 1) * BB * HH;
    if (ownerw) {
      float gi = gsh[(ojj << 3) + ob];
      float gf = gsh[((16 + ojj) << 3) + ob];
      float gg = gsh[((32 + ojj) << 3) + ob];
      float go = gsh[((48 + ojj) << 3) + ob];
      float i_ = sigm(gi), f_ = sigm(gf), g_ = tanh_(gg), o_ = sigm(go);
      cst = __fmaf_rn(f_, cst, i_ * g_);
      float hv = o_ * tanh_(cst);
      // write-through to coherence point; no fence needed
      __hip_atomic_store(&slotp[hoff_owner], hv, __ATOMIC_RELAXED,
                         __HIP_MEMORY_SCOPE_AGENT);
      if (t == TT - 1) { hT[hoff_owner] = hv; cT[hoff_owner] = cst; }
      // drain THIS WAVE's stores, then release this wave's flag (no barrier C)
      asm volatile("s_waitcnt vmcnt(0)" ::: "memory");
      if (lane == 0)
        __hip_atomic_store(&myflags[(sl << 1) + rg], t + 1, __ATOMIC_RELAXED,
                           __HIP_MEMORY_SCOPE_AGENT);
    }

    // ---- deferred: out-projection reduce (off the inter-WG critical path) ----
#pragma unroll
    for (int s = 32; s >= 1; s >>= 1) oacc += __shfl_xor(oacc, s, 64);
    if (t > 0 && lane == 0)
      outp[(size_t)(t - 1) * BB * OO + (bglob0 + rg) * OO + sl] = oacc + bo;
  }

  // ---- final output projection for h_{TT-1} -> outputs[TT-1] ----
  if (rg == 0) {
    int f = __hip_atomic_load(&myflags[lane], __ATOMIC_RELAXED,
                              __HIP_MEMORY_SCOPE_AGENT);
    int guard = 0;
    while (__any(f < TT)) {
      if (++guard > SPIN_LIMIT) break;
      __builtin_amdgcn_s_sleep(1);
      f = __hip_atomic_load(&myflags[lane], __ATOMIC_RELAXED,
                            __HIP_MEMORY_SCOPE_AGENT);
    }
  }
  __syncthreads();
  {
    const float* hsrc = hring + (size_t)((TT - 1) & 1) * BB * HH;
    const float* hb = hsrc + (size_t)(bglob0 + rg) * HH + k0;
    float4 a, b4;
    COH_LOAD4(a, hb);
    COH_LOAD4(b4, hb + 4);
    asm volatile("s_waitcnt vmcnt(0)" ::: "memory");
    __builtin_amdgcn_sched_barrier(0);
    float oacc = a.x * wout[0] + a.y * wout[1] + a.z * wout[2] + a.w * wout[3]
               + b4.x * wout[4] + b4.y * wout[5] + b4.z * wout[6] + b4.w * wout[7];
#pragma unroll
    for (int s = 32; s >= 1; s >>= 1) oacc += __shfl_xor(oacc, s, 64);
    if (lane == 0)
      outp[(size_t)(TT - 1) * BB * OO + (bglob0 + rg) * OO + sl] = oacc + bo;
  }
}

extern "C" void kernel_launch(void* const* d_in, const int* in_sizes, int n_in,
                              void* d_out, int out_size, void* d_ws, size_t ws_size,
                              hipStream_t stream) {
  const float* X    = (const float*)d_in[0];
  const float* h0   = (const float*)d_in[1];
  const float* c0   = (const float*)d_in[2];
  const float* Wih  = (const float*)d_in[3];
  const float* Whh  = (const float*)d_in[4];
  const float* bih  = (const float*)d_in[5];
  const float* bhh  = (const float*)d_in[6];
  const float* Wout = (const float*)d_in[7];
  const float* bout = (const float*)d_in[8];

  float* outp = (float*)d_out;                       // [T][B][OUT]
  float* hT   = outp + (size_t)TT * BB * OO;         // [B][H]
  float* cT   = hT + (size_t)BB * HH;                // [B][H]

  float* hring = (float*)d_ws;                       // 256 KB
  int*   flags = (int*)((char*)d_ws + (size_t)2 * BB * HH * sizeof(float));  // 2 KB

  // flags must be zero at every replay (graph-captured, runs each call)
  hipMemsetAsync(flags, 0, 8 * 64 * sizeof(int), stream);

  lstm_fused<<<dim3(256), dim3(512), 0, stream>>>(
      X, h0, c0, Wih, Whh, bih, bhh, Wout, bout, outp, hT, cT, hring, flags);
}

// Round 13
// 4395.681 us; speedup vs baseline: 2.2282x; 2.0963x over previous
//
#include <hip/hip_runtime.h>

#define TT 2048
#define BB 64
#define INF 32
#define HH 512
#define OO 32

typedef __attribute__((ext_vector_type(8))) short bf16x8;   // 8 bf16 = 4 VGPR
typedef __attribute__((ext_vector_type(4))) float f32x4;    // MFMA acc

__device__ __forceinline__ float sigm(float x) {
  return 1.f / (1.f + __expf(-x));
}
__device__ __forceinline__ float tanh_(float x) {
  float e = __expf(2.f * x);
  return 1.f - 2.f / (1.f + e);
}
// fp32 -> bf16 round-to-nearest-even
__device__ __forceinline__ unsigned short f2bf(float f) {
  unsigned u = __float_as_uint(f);
  u = (u + 0x7FFFu + ((u >> 16) & 1u)) >> 16;
  return (unsigned short)u;
}
__device__ __forceinline__ float bf2f(unsigned short s) {
  return __uint_as_float(((unsigned)s) << 16);
}

// Coherent (L1/L2-bypassing) 16B load from the coherence point (IF$).
#define COH_LOAD4(dst, ptr)                                                  \
  asm volatile("global_load_dwordx4 %0, %1, off sc0 sc1"                     \
               : "=v"(dst) : "v"(ptr))

#define SPIN_LIMIT 20000

// hlds: bf16 [8 batches][512 + 16 pad]  (pad: row stride 1056B -> rows 8
// banks apart -> ds_read_b128 across 8 batches is 2-way = free, m136)
#define HSTR 528

// grid = 256 WGs: bg = blockIdx&7 (8 batches), sl = blockIdx>>3 (16 h-idx).
// 512 thr = 8 waves. R8-VALIDATED sync skeleton (poll/A/stage/A2/B/C/flag).
// NEW compute: waves 0-3 = gate m=rg via MFMA 16x16x32 bf16:
//   A = Whh rows [m*512 + sl*16 + 0..15] x K=512 (bf16, preloaded, 64 VGPR)
//   B = h^T from hlds bf16 (lane: batch=l&7 dup for l&15>=8, junk cols dropped)
//   D lane l, reg r -> row(jj)=(l>>4)*4+r, col(batch)=l&15  [verified m89]
//   +1 MFMA for input projection (A=Wih K=32, B=x_t^T cvt'd per step)
// gsh[gate][jj][batch] identical indices to R8's owner phase (unchanged).
// Waves 4-7: output projection, 2 batches each, from hlds bf16.
// h exchange bf16: even-jj owners pack (jj,jj+1) into one u32 agent store.
//
// RULE-20: all register-array indices compile-time constant after unroll.
__global__ __launch_bounds__(512, 2)
void lstm_fused(const float* __restrict__ X,
                const float* __restrict__ h0,
                const float* __restrict__ c0,
                const float* __restrict__ Wih,
                const float* __restrict__ Whh,
                const float* __restrict__ bih,
                const float* __restrict__ bhh,
                const float* __restrict__ Wout,
                const float* __restrict__ bout,
                float* __restrict__ outp,
                float* __restrict__ hT,
                float* __restrict__ cT,
                unsigned short* __restrict__ hring,  // [2][64][512] bf16
                int* __restrict__ flags)             // [8][32] monotonic
{
  const int tid    = threadIdx.x;
  const int rg     = tid >> 6;
  const int lane   = tid & 63;
  const int bg     = blockIdx.x & 7;
  const int sl     = blockIdx.x >> 3;
  const int bglob0 = bg << 3;

  __shared__ float gsh[512];                              // [gate][jj][b]
  __shared__ __align__(16) unsigned short hlds[8 * HSTR]; // staged h bf16

  const bool mwave = (rg < 4);   // MFMA waves (gate m = rg)

  // ---- per-wave persistent fragments ----
  bf16x8 aW[16], aX;
  float biasf[4];
  if (mwave) {
    const int arow = (rg << 9) + (sl << 4) + (lane & 15);
    const float* wb = Whh + (size_t)arow * HH + ((lane >> 4) << 3);
#pragma unroll
    for (int kt = 0; kt < 16; ++kt) {
      float4 a = ((const float4*)(wb + kt * 32))[0];
      float4 b = ((const float4*)(wb + kt * 32))[1];
      bf16x8 f;
      f[0] = (short)f2bf(a.x); f[1] = (short)f2bf(a.y);
      f[2] = (short)f2bf(a.z); f[3] = (short)f2bf(a.w);
      f[4] = (short)f2bf(b.x); f[5] = (short)f2bf(b.y);
      f[6] = (short)f2bf(b.z); f[7] = (short)f2bf(b.w);
      aW[kt] = f;
    }
    const float* wi = Wih + (size_t)arow * INF + ((lane >> 4) << 3);
    float4 a = ((const float4*)wi)[0];
    float4 b = ((const float4*)wi)[1];
    aX[0] = (short)f2bf(a.x); aX[1] = (short)f2bf(a.y);
    aX[2] = (short)f2bf(a.z); aX[3] = (short)f2bf(a.w);
    aX[4] = (short)f2bf(b.x); aX[5] = (short)f2bf(b.y);
    aX[6] = (short)f2bf(b.z); aX[7] = (short)f2bf(b.w);
#pragma unroll
    for (int r = 0; r < 4; ++r) {
      int rrow = (rg << 9) + (sl << 4) + ((lane >> 4) << 2) + r;
      biasf[r] = bih[rrow] + bhh[rrow];
    }
  }
  float wout[8];
  {
    const float4* wp = (const float4*)(Wout + sl * HH + (lane << 3));
    float4 a = wp[0], b4 = wp[1];
    wout[0] = a.x;  wout[1] = a.y;  wout[2] = a.z;  wout[3] = a.w;
    wout[4] = b4.x; wout[5] = b4.y; wout[6] = b4.z; wout[7] = b4.w;
  }
  const float bo = bout[sl];

  // owners: tid<128, state for (jj = tid>>3, b = tid&7)   [R8-validated]
  const int ojj = tid >> 3, ob = tid & 7;
  const int hoff_owner = (bglob0 + ob) * HH + (sl << 4) + ojj;
  float cst = (tid < 128) ? c0[hoff_owner] : 0.f;

  const int lb = tid >> 6, lg = tid & 63;   // cooperative-stage mapping
  int* myflags = flags + (bg << 5);

  for (int t = 0; t < TT; ++t) {
    // ---- x prefetch for MFMA B-frag (before poll; address-only runtime) ----
    float4 xva, xvb;
    if (mwave) {
      const float* xr = X + (size_t)t * BB * INF + (bglob0 + (lane & 7)) * INF
                        + ((lane >> 4) << 3);
      xva = ((const float4*)xr)[0];
      xvb = ((const float4*)xr)[1];
    }

    // ---- wait for h_{t-1}: wave-0 proxy poll (R8-validated) ----
    if (t > 0 && rg == 0) {
      int f = __hip_atomic_load(&myflags[lane & 31], __ATOMIC_RELAXED,
                                __HIP_MEMORY_SCOPE_AGENT);
      int guard = 0;
      while (__any(f < t)) {
        if (++guard > SPIN_LIMIT) break;
        __builtin_amdgcn_s_sleep(1);
        f = __hip_atomic_load(&myflags[lane & 31], __ATOMIC_RELAXED,
                              __HIP_MEMORY_SCOPE_AGENT);
      }
    }
    __syncthreads();  // barrier A

    // ---- cooperative stage of h_{t-1} (bf16, 8 KB once per WG) ----
    if (t == 0) {
      const float* hp = h0 + (size_t)(bglob0 + lb) * HH + (lg << 3);
      float4 a = ((const float4*)hp)[0];
      float4 b = ((const float4*)hp)[1];
      unsigned d0 = (unsigned)f2bf(a.x) | ((unsigned)f2bf(a.y) << 16);
      unsigned d1 = (unsigned)f2bf(a.z) | ((unsigned)f2bf(a.w) << 16);
      unsigned d2 = (unsigned)f2bf(b.x) | ((unsigned)f2bf(b.y) << 16);
      unsigned d3 = (unsigned)f2bf(b.z) | ((unsigned)f2bf(b.w) << 16);
      *(int4*)(hlds + lb * HSTR + (lg << 3)) = make_int4(d0, d1, d2, d3);
    } else {
      const unsigned short* hsrc = hring + (size_t)((t - 1) & 1) * BB * HH
                                   + (size_t)(bglob0 + lb) * HH + (lg << 3);
      int4 hv;
      COH_LOAD4(hv, hsrc);
      asm volatile("s_waitcnt vmcnt(0)" ::: "memory");
      __builtin_amdgcn_sched_barrier(0);
      *(int4*)(hlds + lb * HSTR + (lg << 3)) = hv;
    }
    __syncthreads();  // barrier A2

    if (mwave) {
      // ---- gate m=rg: 17 MFMAs (input-proj + 16 K-tiles) ----
      f32x4 acc = {0.f, 0.f, 0.f, 0.f};
      bf16x8 bx;
      bx[0] = (short)f2bf(xva.x); bx[1] = (short)f2bf(xva.y);
      bx[2] = (short)f2bf(xva.z); bx[3] = (short)f2bf(xva.w);
      bx[4] = (short)f2bf(xvb.x); bx[5] = (short)f2bf(xvb.y);
      bx[6] = (short)f2bf(xvb.z); bx[7] = (short)f2bf(xvb.w);
      acc = __builtin_amdgcn_mfma_f32_16x16x32_bf16(aX, bx, acc, 0, 0, 0);
      const unsigned short* hb = hlds + (lane & 7) * HSTR + ((lane >> 4) << 3);
#pragma unroll
      for (int kt = 0; kt < 16; ++kt) {
        bf16x8 bf = *(const bf16x8*)(hb + kt * 32);
        acc = __builtin_amdgcn_mfma_f32_16x16x32_bf16(aW[kt], bf, acc, 0, 0, 0);
      }
      if ((lane & 15) < 8) {
        const int gb = (rg << 7) + ((lane >> 4) << 5) + (lane & 15);
#pragma unroll
        for (int r = 0; r < 4; ++r)
          gsh[gb + (r << 3)] = acc[r] + biasf[r];
      }
    } else {
      // ---- output projection for batches 2*(rg-4), +1 (h_{t-1}) ----
      const int wb2 = (rg - 4) << 1;
      const bf16x8 ha = *(const bf16x8*)(hlds + wb2 * HSTR + (lane << 3));
      const bf16x8 hc = *(const bf16x8*)(hlds + (wb2 + 1) * HSTR + (lane << 3));
      float o0 = 0.f, o1 = 0.f;
#pragma unroll
      for (int j = 0; j < 8; ++j) {
        o0 = __fmaf_rn(bf2f((unsigned short)ha[j]), wout[j], o0);
        o1 = __fmaf_rn(bf2f((unsigned short)hc[j]), wout[j], o1);
      }
#pragma unroll
      for (int s = 32; s >= 1; s >>= 1) {
        o0 += __shfl_xor(o0, s, 64);
        o1 += __shfl_xor(o1, s, 64);
      }
      if (t > 0 && lane == 0) {
        outp[(size_t)(t - 1) * BB * OO + (bglob0 + wb2) * OO + sl] = o0 + bo;
        outp[(size_t)(t - 1) * BB * OO + (bglob0 + wb2 + 1) * OO + sl] = o1 + bo;
      }
    }
    __syncthreads();  // barrier B

    // ---- owners: nonlinearity, c/h update, packed bf16 publish ----
    if (tid < 128) {
      float gi = gsh[(ojj << 3) + ob];
      float gf = gsh[128 + (ojj << 3) + ob];
      float gg = gsh[256 + (ojj << 3) + ob];
      float go = gsh[384 + (ojj << 3) + ob];
      float i_ = sigm(gi), f_ = sigm(gf), g_ = tanh_(gg), o_ = sigm(go);
      cst = __fmaf_rn(f_, cst, i_ * g_);
      float hv = o_ * tanh_(cst);
      float hv2 = __shfl(hv, (lane + 8) & 63, 64);  // partner jj+1 (same wave)
      if ((lane & 8) == 0) {
        unsigned pk = (unsigned)f2bf(hv) | ((unsigned)f2bf(hv2) << 16);
        unsigned* slot32 = (unsigned*)(hring + (size_t)(t & 1) * BB * HH);
        __hip_atomic_store(&slot32[((bglob0 + ob) << 8) + (sl << 3) + (ojj >> 1)],
                           pk, __ATOMIC_RELAXED, __HIP_MEMORY_SCOPE_AGENT);
      }
      if (t == TT - 1) { hT[hoff_owner] = hv; cT[hoff_owner] = cst; }
    }
    __syncthreads();  // barrier C: drains owners' stores before flag
    if (tid == 0)
      __hip_atomic_store(&myflags[sl], t + 1, __ATOMIC_RELAXED,
                         __HIP_MEMORY_SCOPE_AGENT);
  }

  // ---- final output projection for h_{TT-1} -> outputs[TT-1] ----
  if (rg == 0) {
    int f = __hip_atomic_load(&myflags[lane & 31], __ATOMIC_RELAXED,
                              __HIP_MEMORY_SCOPE_AGENT);
    int guard = 0;
    while (__any(f < TT)) {
      if (++guard > SPIN_LIMIT) break;
      __builtin_amdgcn_s_sleep(1);
      f = __hip_atomic_load(&myflags[lane & 31], __ATOMIC_RELAXED,
                            __HIP_MEMORY_SCOPE_AGENT);
    }
  }
  __syncthreads();
  {
    const unsigned short* hb = hring + (size_t)((TT - 1) & 1) * BB * HH
                               + (size_t)(bglob0 + rg) * HH + (lane << 3);
    int4 p;
    COH_LOAD4(p, hb);
    asm volatile("s_waitcnt vmcnt(0)" ::: "memory");
    __builtin_amdgcn_sched_barrier(0);
    float oacc =
        __uint_as_float(((unsigned)p.x) << 16)        * wout[0] +
        __uint_as_float(((unsigned)p.x) & 0xFFFF0000u) * wout[1] +
        __uint_as_float(((unsigned)p.y) << 16)        * wout[2] +
        __uint_as_float(((unsigned)p.y) & 0xFFFF0000u) * wout[3] +
        __uint_as_float(((unsigned)p.z) << 16)        * wout[4] +
        __uint_as_float(((unsigned)p.z) & 0xFFFF0000u) * wout[5] +
        __uint_as_float(((unsigned)p.w) << 16)        * wout[6] +
        __uint_as_float(((unsigned)p.w) & 0xFFFF0000u) * wout[7];
#pragma unroll
    for (int s = 32; s >= 1; s >>= 1) oacc += __shfl_xor(oacc, s, 64);
    if (lane == 0)
      outp[(size_t)(TT - 1) * BB * OO + (bglob0 + rg) * OO + sl] = oacc + bo;
  }
}

extern "C" void kernel_launch(void* const* d_in, const int* in_sizes, int n_in,
                              void* d_out, int out_size, void* d_ws, size_t ws_size,
                              hipStream_t stream) {
  const float* X    = (const float*)d_in[0];
  const float* h0   = (const float*)d_in[1];
  const float* c0   = (const float*)d_in[2];
  const float* Wih  = (const float*)d_in[3];
  const float* Whh  = (const float*)d_in[4];
  const float* bih  = (const float*)d_in[5];
  const float* bhh  = (const float*)d_in[6];
  const float* Wout = (const float*)d_in[7];
  const float* bout = (const float*)d_in[8];

  float* outp = (float*)d_out;                       // [T][B][OUT]
  float* hT   = outp + (size_t)TT * BB * OO;         // [B][H]
  float* cT   = hT + (size_t)BB * HH;                // [B][H]

  unsigned short* hring = (unsigned short*)d_ws;     // 2*64*512*2 = 128 KB
  int* flags = (int*)((char*)d_ws + (size_t)2 * BB * HH * sizeof(unsigned short));

  // flags must be zero at every replay (graph-captured, runs each call)
  hipMemsetAsync(flags, 0, 8 * 32 * sizeof(int), stream);

  lstm_fused<<<dim3(256), dim3(512), 0, stream>>>(
      X, h0, c0, Wih, Whh, bih, bhh, Wout, bout, outp, hT, cT, hring, flags);
}

// Round 14
// 4122.394 us; speedup vs baseline: 2.3759x; 1.0663x over previous
//
#include <hip/hip_runtime.h>

#define TT 2048
#define BB 64
#define INF 32
#define HH 512
#define OO 32

typedef __attribute__((ext_vector_type(8))) short bf16x8;   // 8 bf16 = 4 VGPR
typedef __attribute__((ext_vector_type(4))) float f32x4;    // MFMA acc

__device__ __forceinline__ float sigm(float x) {
  return 1.f / (1.f + __expf(-x));
}
__device__ __forceinline__ float tanh_(float x) {
  float e = __expf(2.f * x);
  return 1.f - 2.f / (1.f + e);
}
// fp32 -> bf16 round-to-nearest-even
__device__ __forceinline__ unsigned short f2bf(float f) {
  unsigned u = __float_as_uint(f);
  u = (u + 0x7FFFu + ((u >> 16) & 1u)) >> 16;
  return (unsigned short)u;
}
__device__ __forceinline__ float bf2f(unsigned short s) {
  return __uint_as_float(((unsigned)s) << 16);
}

// Coherent (L1/L2-bypassing) 16B load from the coherence point (IF$).
#define COH_LOAD4(dst, ptr)                                                  \
  asm volatile("global_load_dwordx4 %0, %1, off sc0 sc1"                     \
               : "=v"(dst) : "v"(ptr))

#define SPIN_LIMIT 20000

#define HSTR 528   // bf16 row stride (measured R13: conflicts negligible)

// grid = 256 WGs: bg = blockIdx&7 (8 batches), sl = blockIdx>>3 (16 h-idx).
// 512 thr = 8 waves. R8-validated sync skeleton; R13-validated MFMA frags.
//
// R14 gate-bundled A-row permutation: wave rg (0-3) computes ALL 4 gates for
// jj in {4rg..4rg+3}. A row ri (0..15) = Whh row
//   grow(ri) = (ri&3)*512 + sl*16 + rg*4 + (ri>>2)    [gate=ri&3, jj_off=ri>>2]
// D layout (m89/R13-verified): lane l, reg r -> row=(l>>4)*4+r, col=l&15.
// => lane l holds {i,f,g,o} = acc[0..3] for (jj = 4rg + (l>>4), b = l&15).
// Nonlinearity + c/h update fully in-lane: NO gsh, NO barrier B.
// Waves 4-7: output projection (2 batches each), store deferred past flag.
//
// RULE-20: all register-array indices compile-time constant after unroll.
__global__ __launch_bounds__(512, 2)
void lstm_fused(const float* __restrict__ X,
                const float* __restrict__ h0,
                const float* __restrict__ c0,
                const float* __restrict__ Wih,
                const float* __restrict__ Whh,
                const float* __restrict__ bih,
                const float* __restrict__ bhh,
                const float* __restrict__ Wout,
                const float* __restrict__ bout,
                float* __restrict__ outp,
                float* __restrict__ hT,
                float* __restrict__ cT,
                unsigned short* __restrict__ hring,  // [2][64][512] bf16
                int* __restrict__ flags)             // [8][32] monotonic
{
  const int tid    = threadIdx.x;
  const int rg     = tid >> 6;
  const int lane   = tid & 63;
  const int bg     = blockIdx.x & 7;
  const int sl     = blockIdx.x >> 3;
  const int bglob0 = bg << 3;

  __shared__ __align__(16) unsigned short hlds[8 * HSTR]; // staged h bf16

  const bool mwave = (rg < 4);

  // ---- per-wave persistent fragments (gate-bundled row permutation) ----
  bf16x8 aW[16], aX;
  float biasf[4];
  if (mwave) {
    const int ri = lane & 15;
    const int arow = ((ri & 3) << 9) + (sl << 4) + (rg << 2) + (ri >> 2);
    const float* wb = Whh + (size_t)arow * HH + ((lane >> 4) << 3);
#pragma unroll
    for (int kt = 0; kt < 16; ++kt) {
      float4 a = ((const float4*)(wb + kt * 32))[0];
      float4 b = ((const float4*)(wb + kt * 32))[1];
      bf16x8 f;
      f[0] = (short)f2bf(a.x); f[1] = (short)f2bf(a.y);
      f[2] = (short)f2bf(a.z); f[3] = (short)f2bf(a.w);
      f[4] = (short)f2bf(b.x); f[5] = (short)f2bf(b.y);
      f[6] = (short)f2bf(b.z); f[7] = (short)f2bf(b.w);
      aW[kt] = f;
    }
    const float* wi = Wih + (size_t)arow * INF + ((lane >> 4) << 3);
    float4 a = ((const float4*)wi)[0];
    float4 b = ((const float4*)wi)[1];
    aX[0] = (short)f2bf(a.x); aX[1] = (short)f2bf(a.y);
    aX[2] = (short)f2bf(a.z); aX[3] = (short)f2bf(a.w);
    aX[4] = (short)f2bf(b.x); aX[5] = (short)f2bf(b.y);
    aX[6] = (short)f2bf(b.z); aX[7] = (short)f2bf(b.w);
    // bias for this lane's D rows: gate=r, jj = rg*4 + (lane>>4)
#pragma unroll
    for (int r = 0; r < 4; ++r) {
      int grow = (r << 9) + (sl << 4) + (rg << 2) + (lane >> 4);
      biasf[r] = bih[grow] + bhh[grow];
    }
  }
  float wout[8];
  {
    const float4* wp = (const float4*)(Wout + sl * HH + (lane << 3));
    float4 a = wp[0], b4 = wp[1];
    wout[0] = a.x;  wout[1] = a.y;  wout[2] = a.z;  wout[3] = a.w;
    wout[4] = b4.x; wout[5] = b4.y; wout[6] = b4.z; wout[7] = b4.w;
  }
  const float bo = bout[sl];

  // owner lanes: mwave && (lane&15)<8 -> (jj = 4rg + (lane>>4), b = lane&7)
  const bool owner = mwave && ((lane & 15) < 8);
  const int ob = lane & 7;
  const int ojj = (rg << 2) + (lane >> 4);
  const int hoff_owner = (bglob0 + ob) * HH + (sl << 4) + ojj;
  float cst = owner ? c0[hoff_owner] : 0.f;

  const int lb = tid >> 6, lg = tid & 63;   // cooperative-stage mapping
  int* myflags = flags + (bg << 5);

  for (int t = 0; t < TT; ++t) {
    // ---- x prefetch for MFMA B-frag (before poll; address-only runtime) ----
    float4 xva, xvb;
    if (mwave) {
      const float* xr = X + (size_t)t * BB * INF + (bglob0 + (lane & 7)) * INF
                        + ((lane >> 4) << 3);
      xva = ((const float4*)xr)[0];
      xvb = ((const float4*)xr)[1];
    }

    // ---- wait for h_{t-1}: wave-0 proxy poll (R8-validated) ----
    if (t > 0 && rg == 0) {
      int f = __hip_atomic_load(&myflags[lane & 31], __ATOMIC_RELAXED,
                                __HIP_MEMORY_SCOPE_AGENT);
      int guard = 0;
      while (__any(f < t)) {
        if (++guard > SPIN_LIMIT) break;
        __builtin_amdgcn_s_sleep(1);
        f = __hip_atomic_load(&myflags[lane & 31], __ATOMIC_RELAXED,
                              __HIP_MEMORY_SCOPE_AGENT);
      }
    }
    __syncthreads();  // barrier A

    // ---- cooperative stage of h_{t-1} (bf16, 8 KB once per WG) ----
    if (t == 0) {
      const float* hp = h0 + (size_t)(bglob0 + lb) * HH + (lg << 3);
      float4 a = ((const float4*)hp)[0];
      float4 b = ((const float4*)hp)[1];
      unsigned d0 = (unsigned)f2bf(a.x) | ((unsigned)f2bf(a.y) << 16);
      unsigned d1 = (unsigned)f2bf(a.z) | ((unsigned)f2bf(a.w) << 16);
      unsigned d2 = (unsigned)f2bf(b.x) | ((unsigned)f2bf(b.y) << 16);
      unsigned d3 = (unsigned)f2bf(b.z) | ((unsigned)f2bf(b.w) << 16);
      *(int4*)(hlds + lb * HSTR + (lg << 3)) = make_int4(d0, d1, d2, d3);
    } else {
      const unsigned short* hsrc = hring + (size_t)((t - 1) & 1) * BB * HH
                                   + (size_t)(bglob0 + lb) * HH + (lg << 3);
      int4 hv;
      COH_LOAD4(hv, hsrc);
      asm volatile("s_waitcnt vmcnt(0)" ::: "memory");
      __builtin_amdgcn_sched_barrier(0);
      *(int4*)(hlds + lb * HSTR + (lg << 3)) = hv;
    }
    __syncthreads();  // barrier A2

    float o0 = 0.f, o1 = 0.f;   // out-proj partials (waves 4-7)
    if (mwave) {
      // ---- all 4 gates for jj in {4rg..4rg+3}: 17 MFMAs ----
      f32x4 acc = {0.f, 0.f, 0.f, 0.f};
      bf16x8 bx;
      bx[0] = (short)f2bf(xva.x); bx[1] = (short)f2bf(xva.y);
      bx[2] = (short)f2bf(xva.z); bx[3] = (short)f2bf(xva.w);
      bx[4] = (short)f2bf(xvb.x); bx[5] = (short)f2bf(xvb.y);
      bx[6] = (short)f2bf(xvb.z); bx[7] = (short)f2bf(xvb.w);
      acc = __builtin_amdgcn_mfma_f32_16x16x32_bf16(aX, bx, acc, 0, 0, 0);
      const unsigned short* hb = hlds + (lane & 7) * HSTR + ((lane >> 4) << 3);
#pragma unroll
      for (int kt = 0; kt < 16; ++kt) {
        bf16x8 bf = *(const bf16x8*)(hb + kt * 32);
        acc = __builtin_amdgcn_mfma_f32_16x16x32_bf16(aW[kt], bf, acc, 0, 0, 0);
      }
      // ---- in-lane gates -> c/h update -> packed bf16 publish ----
      float i_ = sigm(acc[0] + biasf[0]);
      float f_ = sigm(acc[1] + biasf[1]);
      float g_ = tanh_(acc[2] + biasf[2]);
      float o_ = sigm(acc[3] + biasf[3]);
      float cnew = __fmaf_rn(f_, cst, i_ * g_);
      float hv = o_ * tanh_(cnew);
      if (owner) cst = cnew;
      float hv2 = __shfl(hv, (lane + 16) & 63, 64);  // partner jj_off+1
      if (owner && ((lane >> 4) & 1) == 0) {
        unsigned pk = (unsigned)f2bf(hv) | ((unsigned)f2bf(hv2) << 16);
        unsigned* slot32 = (unsigned*)(hring + (size_t)(t & 1) * BB * HH);
        __hip_atomic_store(
            &slot32[((bglob0 + ob) << 8) + (sl << 3) + (rg << 1) + (lane >> 5)],
            pk, __ATOMIC_RELAXED, __HIP_MEMORY_SCOPE_AGENT);
      }
      if (owner && t == TT - 1) { hT[hoff_owner] = hv; cT[hoff_owner] = cst; }
    } else {
      // ---- output projection for batches 2*(rg-4), +1 (h_{t-1}) ----
      const int wb2 = (rg - 4) << 1;
      const bf16x8 ha = *(const bf16x8*)(hlds + wb2 * HSTR + (lane << 3));
      const bf16x8 hc = *(const bf16x8*)(hlds + (wb2 + 1) * HSTR + (lane << 3));
#pragma unroll
      for (int j = 0; j < 8; ++j) {
        o0 = __fmaf_rn(bf2f((unsigned short)ha[j]), wout[j], o0);
        o1 = __fmaf_rn(bf2f((unsigned short)hc[j]), wout[j], o1);
      }
#pragma unroll
      for (int s = 32; s >= 1; s >>= 1) {
        o0 += __shfl_xor(o0, s, 64);
        o1 += __shfl_xor(o1, s, 64);
      }
    }
    __syncthreads();  // barrier C: drains owners' h stores before flag
    if (tid == 0)
      __hip_atomic_store(&myflags[sl], t + 1, __ATOMIC_RELAXED,
                         __HIP_MEMORY_SCOPE_AGENT);
    // ---- deferred outp store (drains during next step's slack) ----
    if (!mwave && t > 0 && lane == 0) {
      const int wb2 = (rg - 4) << 1;
      outp[(size_t)(t - 1) * BB * OO + (bglob0 + wb2) * OO + sl] = o0 + bo;
      outp[(size_t)(t - 1) * BB * OO + (bglob0 + wb2 + 1) * OO + sl] = o1 + bo;
    }
  }

  // ---- final output projection for h_{TT-1} -> outputs[TT-1] ----
  if (rg == 0) {
    int f = __hip_atomic_load(&myflags[lane & 31], __ATOMIC_RELAXED,
                              __HIP_MEMORY_SCOPE_AGENT);
    int guard = 0;
    while (__any(f < TT)) {
      if (++guard > SPIN_LIMIT) break;
      __builtin_amdgcn_s_sleep(1);
      f = __hip_atomic_load(&myflags[lane & 31], __ATOMIC_RELAXED,
                            __HIP_MEMORY_SCOPE_AGENT);
    }
  }
  __syncthreads();
  {
    const unsigned short* hb = hring + (size_t)((TT - 1) & 1) * BB * HH
                               + (size_t)(bglob0 + rg) * HH + (lane << 3);
    int4 p;
    COH_LOAD4(p, hb);
    asm volatile("s_waitcnt vmcnt(0)" ::: "memory");
    __builtin_amdgcn_sched_barrier(0);
    float oacc =
        __uint_as_float(((unsigned)p.x) << 16)        * wout[0] +
        __uint_as_float(((unsigned)p.x) & 0xFFFF0000u) * wout[1] +
        __uint_as_float(((unsigned)p.y) << 16)        * wout[2] +
        __uint_as_float(((unsigned)p.y) & 0xFFFF0000u) * wout[3] +
        __uint_as_float(((unsigned)p.z) << 16)        * wout[4] +
        __uint_as_float(((unsigned)p.z) & 0xFFFF0000u) * wout[5] +
        __uint_as_float(((unsigned)p.w) << 16)        * wout[6] +
        __uint_as_float(((unsigned)p.w) & 0xFFFF0000u) * wout[7];
#pragma unroll
    for (int s = 32; s >= 1; s >>= 1) oacc += __shfl_xor(oacc, s, 64);
    if (lane == 0)
      outp[(size_t)(TT - 1) * BB * OO + (bglob0 + rg) * OO + sl] = oacc + bo;
  }
}

extern "C" void kernel_launch(void* const* d_in, const int* in_sizes, int n_in,
                              void* d_out, int out_size, void* d_ws, size_t ws_size,
                              hipStream_t stream) {
  const float* X    = (const float*)d_in[0];
  const float* h0   = (const float*)d_in[1];
  const float* c0   = (const float*)d_in[2];
  const float* Wih  = (const float*)d_in[3];
  const float* Whh  = (const float*)d_in[4];
  const float* bih  = (const float*)d_in[5];
  const float* bhh  = (const float*)d_in[6];
  const float* Wout = (const float*)d_in[7];
  const float* bout = (const float*)d_in[8];

  float* outp = (float*)d_out;                       // [T][B][OUT]
  float* hT   = outp + (size_t)TT * BB * OO;         // [B][H]
  float* cT   = hT + (size_t)BB * HH;                // [B][H]

  unsigned short* hring = (unsigned short*)d_ws;     // 128 KB
  int* flags = (int*)((char*)d_ws + (size_t)2 * BB * HH * sizeof(unsigned short));

  // flags must be zero at every replay (graph-captured, runs each call)
  hipMemsetAsync(flags, 0, 8 * 32 * sizeof(int), stream);

  lstm_fused<<<dim3(256), dim3(512), 0, stream>>>(
      X, h0, c0, Wih, Whh, bih, bhh, Wout, bout, outp, hT, cT, hring, flags);
}

// Round 15
// 3961.424 us; speedup vs baseline: 2.4724x; 1.0406x over previous
//
#include <hip/hip_runtime.h>

#define TT 2048
#define BB 64
#define INF 32
#define HH 512
#define OO 32

typedef __attribute__((ext_vector_type(8))) short bf16x8;   // 8 bf16 = 4 VGPR
typedef __attribute__((ext_vector_type(4))) float f32x4;    // MFMA acc

__device__ __forceinline__ float sigm(float x) {
  return 1.f / (1.f + __expf(-x));
}
__device__ __forceinline__ float tanh_(float x) {
  float e = __expf(2.f * x);
  return 1.f - 2.f / (1.f + e);
}
// fp32 -> bf16 round-to-nearest-even
__device__ __forceinline__ unsigned short f2bf(float f) {
  unsigned u = __float_as_uint(f);
  u = (u + 0x7FFFu + ((u >> 16) & 1u)) >> 16;
  return (unsigned short)u;
}
__device__ __forceinline__ float bf2f(unsigned short s) {
  return __uint_as_float(((unsigned)s) << 16);
}

// Coherent (L1/L2-bypassing) 16B load from the coherence point (IF$).
#define COH_LOAD4(dst, ptr)                                                  \
  asm volatile("global_load_dwordx4 %0, %1, off sc0 sc1"                     \
               : "=v"(dst) : "v"(ptr))

#define SPIN_LIMIT 20000

#define HSTR 528   // bf16 row stride (measured R13/R14: conflicts ~0)

// grid = 256 WGs: bg = blockIdx&7 (8 batches), sl = blockIdx>>3 (16 h-idx).
// 512 thr = 8 waves. R13/R14-validated MFMA fragments + gate-bundled rows:
//   wave rg (0-3): A row ri = Whh row (ri&3)*512 + sl*16 + rg*4 + (ri>>2)
//   D (m89-verified): lane l, reg r -> row=(l>>4)*4+r, col=l&15
//   => lane holds {i,f,g,o} for (jj = 4rg + (l>>4), b = l&15) in-lane.
// R15: (1) ALL-WAVE poll, barrier A removed — flag->stage ordering is
// per-wave (loop exit waits on poll load; stage issued after); hlds WAR is
// ordered by barrier C (all reads of t-1 precede C(t-1) precede stage(t)).
// (2) MFMA split into 2 independent chains (even/odd kt) to halve the
// dependent-latency chain. (3) x bf16 conversion hoisted pre-poll.
// Barriers/step: A2, C only.
//
// RULE-20: all register-array indices compile-time constant after unroll.
__global__ __launch_bounds__(512, 2)
void lstm_fused(const float* __restrict__ X,
                const float* __restrict__ h0,
                const float* __restrict__ c0,
                const float* __restrict__ Wih,
                const float* __restrict__ Whh,
                const float* __restrict__ bih,
                const float* __restrict__ bhh,
                const float* __restrict__ Wout,
                const float* __restrict__ bout,
                float* __restrict__ outp,
                float* __restrict__ hT,
                float* __restrict__ cT,
                unsigned short* __restrict__ hring,  // [2][64][512] bf16
                int* __restrict__ flags)             // [8][32] monotonic
{
  const int tid    = threadIdx.x;
  const int rg     = tid >> 6;
  const int lane   = tid & 63;
  const int bg     = blockIdx.x & 7;
  const int sl     = blockIdx.x >> 3;
  const int bglob0 = bg << 3;

  __shared__ __align__(16) unsigned short hlds[8 * HSTR]; // staged h bf16

  const bool mwave = (rg < 4);

  // ---- per-wave persistent fragments (gate-bundled row permutation) ----
  bf16x8 aW[16], aX;
  float biasf[4];
  if (mwave) {
    const int ri = lane & 15;
    const int arow = ((ri & 3) << 9) + (sl << 4) + (rg << 2) + (ri >> 2);
    const float* wb = Whh + (size_t)arow * HH + ((lane >> 4) << 3);
#pragma unroll
    for (int kt = 0; kt < 16; ++kt) {
      float4 a = ((const float4*)(wb + kt * 32))[0];
      float4 b = ((const float4*)(wb + kt * 32))[1];
      bf16x8 f;
      f[0] = (short)f2bf(a.x); f[1] = (short)f2bf(a.y);
      f[2] = (short)f2bf(a.z); f[3] = (short)f2bf(a.w);
      f[4] = (short)f2bf(b.x); f[5] = (short)f2bf(b.y);
      f[6] = (short)f2bf(b.z); f[7] = (short)f2bf(b.w);
      aW[kt] = f;
    }
    const float* wi = Wih + (size_t)arow * INF + ((lane >> 4) << 3);
    float4 a = ((const float4*)wi)[0];
    float4 b = ((const float4*)wi)[1];
    aX[0] = (short)f2bf(a.x); aX[1] = (short)f2bf(a.y);
    aX[2] = (short)f2bf(a.z); aX[3] = (short)f2bf(a.w);
    aX[4] = (short)f2bf(b.x); aX[5] = (short)f2bf(b.y);
    aX[6] = (short)f2bf(b.z); aX[7] = (short)f2bf(b.w);
#pragma unroll
    for (int r = 0; r < 4; ++r) {
      int grow = (r << 9) + (sl << 4) + (rg << 2) + (lane >> 4);
      biasf[r] = bih[grow] + bhh[grow];
    }
  }
  float wout[8];
  {
    const float4* wp = (const float4*)(Wout + sl * HH + (lane << 3));
    float4 a = wp[0], b4 = wp[1];
    wout[0] = a.x;  wout[1] = a.y;  wout[2] = a.z;  wout[3] = a.w;
    wout[4] = b4.x; wout[5] = b4.y; wout[6] = b4.z; wout[7] = b4.w;
  }
  const float bo = bout[sl];

  // owner lanes: mwave && (lane&15)<8 -> (jj = 4rg + (lane>>4), b = lane&7)
  const bool owner = mwave && ((lane & 15) < 8);
  const int ob = lane & 7;
  const int ojj = (rg << 2) + (lane >> 4);
  const int hoff_owner = (bglob0 + ob) * HH + (sl << 4) + ojj;
  float cst = owner ? c0[hoff_owner] : 0.f;

  const int lb = tid >> 6, lg = tid & 63;   // cooperative-stage mapping
  int* myflags = flags + (bg << 5);

  for (int t = 0; t < TT; ++t) {
    // ---- x prefetch + bf16 convert (h-independent; hidden under poll) ----
    bf16x8 bx;
    if (mwave) {
      const float* xr = X + (size_t)t * BB * INF + (bglob0 + (lane & 7)) * INF
                        + ((lane >> 4) << 3);
      float4 xva = ((const float4*)xr)[0];
      float4 xvb = ((const float4*)xr)[1];
      bx[0] = (short)f2bf(xva.x); bx[1] = (short)f2bf(xva.y);
      bx[2] = (short)f2bf(xva.z); bx[3] = (short)f2bf(xva.w);
      bx[4] = (short)f2bf(xvb.x); bx[5] = (short)f2bf(xvb.y);
      bx[6] = (short)f2bf(xvb.z); bx[7] = (short)f2bf(xvb.w);
    }

    // ---- ALL-WAVE poll for h_{t-1} (no barrier A) ----
    if (t > 0) {
      int f = __hip_atomic_load(&myflags[lane & 31], __ATOMIC_RELAXED,
                                __HIP_MEMORY_SCOPE_AGENT);
      int guard = 0;
      while (__any(f < t)) {
        if (++guard > SPIN_LIMIT) break;
        __builtin_amdgcn_s_sleep(1);
        f = __hip_atomic_load(&myflags[lane & 31], __ATOMIC_RELAXED,
                              __HIP_MEMORY_SCOPE_AGENT);
      }
    }

    // ---- cooperative stage of h_{t-1} (bf16, 8 KB once per WG) ----
    if (t == 0) {
      const float* hp = h0 + (size_t)(bglob0 + lb) * HH + (lg << 3);
      float4 a = ((const float4*)hp)[0];
      float4 b = ((const float4*)hp)[1];
      unsigned d0 = (unsigned)f2bf(a.x) | ((unsigned)f2bf(a.y) << 16);
      unsigned d1 = (unsigned)f2bf(a.z) | ((unsigned)f2bf(a.w) << 16);
      unsigned d2 = (unsigned)f2bf(b.x) | ((unsigned)f2bf(b.y) << 16);
      unsigned d3 = (unsigned)f2bf(b.z) | ((unsigned)f2bf(b.w) << 16);
      *(int4*)(hlds + lb * HSTR + (lg << 3)) = make_int4(d0, d1, d2, d3);
    } else {
      const unsigned short* hsrc = hring + (size_t)((t - 1) & 1) * BB * HH
                                   + (size_t)(bglob0 + lb) * HH + (lg << 3);
      int4 hv;
      COH_LOAD4(hv, hsrc);
      asm volatile("s_waitcnt vmcnt(0)" ::: "memory");
      __builtin_amdgcn_sched_barrier(0);
      *(int4*)(hlds + lb * HSTR + (lg << 3)) = hv;
    }
    __syncthreads();  // barrier A2: staged h visible to all waves

    float o0 = 0.f, o1 = 0.f;   // out-proj partials (waves 4-7)
    if (mwave) {
      // ---- 4 gates for jj in {4rg..4rg+3}: 17 MFMAs, 2 indep chains ----
      f32x4 acc0 = {0.f, 0.f, 0.f, 0.f};
      f32x4 acc1 = {0.f, 0.f, 0.f, 0.f};
      acc0 = __builtin_amdgcn_mfma_f32_16x16x32_bf16(aX, bx, acc0, 0, 0, 0);
      const unsigned short* hb = hlds + (lane & 7) * HSTR + ((lane >> 4) << 3);
#pragma unroll
      for (int kt = 0; kt < 16; kt += 2) {
        bf16x8 bf0 = *(const bf16x8*)(hb + kt * 32);
        bf16x8 bf1 = *(const bf16x8*)(hb + (kt + 1) * 32);
        acc0 = __builtin_amdgcn_mfma_f32_16x16x32_bf16(aW[kt], bf0, acc0, 0, 0, 0);
        acc1 = __builtin_amdgcn_mfma_f32_16x16x32_bf16(aW[kt + 1], bf1, acc1, 0, 0, 0);
      }
      // ---- in-lane gates -> c/h update -> packed bf16 publish ----
      float i_ = sigm(acc0[0] + acc1[0] + biasf[0]);
      float f_ = sigm(acc0[1] + acc1[1] + biasf[1]);
      float g_ = tanh_(acc0[2] + acc1[2] + biasf[2]);
      float o_ = sigm(acc0[3] + acc1[3] + biasf[3]);
      float cnew = __fmaf_rn(f_, cst, i_ * g_);
      float hv = o_ * tanh_(cnew);
      if (owner) cst = cnew;
      float hv2 = __shfl(hv, (lane + 16) & 63, 64);  // partner jj_off+1
      if (owner && ((lane >> 4) & 1) == 0) {
        unsigned pk = (unsigned)f2bf(hv) | ((unsigned)f2bf(hv2) << 16);
        unsigned* slot32 = (unsigned*)(hring + (size_t)(t & 1) * BB * HH);
        __hip_atomic_store(
            &slot32[((bglob0 + ob) << 8) + (sl << 3) + (rg << 1) + (lane >> 5)],
            pk, __ATOMIC_RELAXED, __HIP_MEMORY_SCOPE_AGENT);
      }
      if (owner && t == TT - 1) { hT[hoff_owner] = hv; cT[hoff_owner] = cst; }
    } else {
      // ---- output projection for batches 2*(rg-4), +1 (h_{t-1}) ----
      const int wb2 = (rg - 4) << 1;
      const bf16x8 ha = *(const bf16x8*)(hlds + wb2 * HSTR + (lane << 3));
      const bf16x8 hc = *(const bf16x8*)(hlds + (wb2 + 1) * HSTR + (lane << 3));
#pragma unroll
      for (int j = 0; j < 8; ++j) {
        o0 = __fmaf_rn(bf2f((unsigned short)ha[j]), wout[j], o0);
        o1 = __fmaf_rn(bf2f((unsigned short)hc[j]), wout[j], o1);
      }
#pragma unroll
      for (int s = 32; s >= 1; s >>= 1) {
        o0 += __shfl_xor(o0, s, 64);
        o1 += __shfl_xor(o1, s, 64);
      }
    }
    __syncthreads();  // barrier C: drains owners' h stores before flag
    if (tid == 0)
      __hip_atomic_store(&myflags[sl], t + 1, __ATOMIC_RELAXED,
                         __HIP_MEMORY_SCOPE_AGENT);
    // ---- deferred outp store (drains during next step's slack) ----
    if (!mwave && t > 0 && lane == 0) {
      const int wb2 = (rg - 4) << 1;
      outp[(size_t)(t - 1) * BB * OO + (bglob0 + wb2) * OO + sl] = o0 + bo;
      outp[(size_t)(t - 1) * BB * OO + (bglob0 + wb2 + 1) * OO + sl] = o1 + bo;
    }
  }

  // ---- final output projection for h_{TT-1} -> outputs[TT-1] ----
  {
    int f = __hip_atomic_load(&myflags[lane & 31], __ATOMIC_RELAXED,
                              __HIP_MEMORY_SCOPE_AGENT);
    int guard = 0;
    while (__any(f < TT)) {
      if (++guard > SPIN_LIMIT) break;
      __builtin_amdgcn_s_sleep(1);
      f = __hip_atomic_load(&myflags[lane & 31], __ATOMIC_RELAXED,
                            __HIP_MEMORY_SCOPE_AGENT);
    }
  }
  {
    const unsigned short* hb = hring + (size_t)((TT - 1) & 1) * BB * HH
                               + (size_t)(bglob0 + rg) * HH + (lane << 3);
    int4 p;
    COH_LOAD4(p, hb);
    asm volatile("s_waitcnt vmcnt(0)" ::: "memory");
    __builtin_amdgcn_sched_barrier(0);
    float oacc =
        __uint_as_float(((unsigned)p.x) << 16)        * wout[0] +
        __uint_as_float(((unsigned)p.x) & 0xFFFF0000u) * wout[1] +
        __uint_as_float(((unsigned)p.y) << 16)        * wout[2] +
        __uint_as_float(((unsigned)p.y) & 0xFFFF0000u) * wout[3] +
        __uint_as_float(((unsigned)p.z) << 16)        * wout[4] +
        __uint_as_float(((unsigned)p.z) & 0xFFFF0000u) * wout[5] +
        __uint_as_float(((unsigned)p.w) << 16)        * wout[6] +
        __uint_as_float(((unsigned)p.w) & 0xFFFF0000u) * wout[7];
#pragma unroll
    for (int s = 32; s >= 1; s >>= 1) oacc += __shfl_xor(oacc, s, 64);
    if (lane == 0)
      outp[(size_t)(TT - 1) * BB * OO + (bglob0 + rg) * OO + sl] = oacc + bo;
  }
}

extern "C" void kernel_launch(void* const* d_in, const int* in_sizes, int n_in,
                              void* d_out, int out_size, void* d_ws, size_t ws_size,
                              hipStream_t stream) {
  const float* X    = (const float*)d_in[0];
  const float* h0   = (const float*)d_in[1];
  const float* c0   = (const float*)d_in[2];
  const float* Wih  = (const float*)d_in[3];
  const float* Whh  = (const float*)d_in[4];
  const float* bih  = (const float*)d_in[5];
  const float* bhh  = (const float*)d_in[6];
  const float* Wout = (const float*)d_in[7];
  const float* bout = (const float*)d_in[8];

  float* outp = (float*)d_out;                       // [T][B][OUT]
  float* hT   = outp + (size_t)TT * BB * OO;         // [B][H]
  float* cT   = hT + (size_t)BB * HH;                // [B][H]

  unsigned short* hring = (unsigned short*)d_ws;     // 128 KB
  int* flags = (int*)((char*)d_ws + (size_t)2 * BB * HH * sizeof(unsigned short));

  // flags must be zero at every replay (graph-captured, runs each call)
  hipMemsetAsync(flags, 0, 8 * 32 * sizeof(int), stream);

  lstm_fused<<<dim3(256), dim3(512), 0, stream>>>(
      X, h0, c0, Wih, Whh, bih, bhh, Wout, bout, outp, hT, cT, hring, flags);
}